// Round 1
// baseline (1095.887 us; speedup 1.0000x reference)
//
#include <hip/hip_runtime.h>

#define GN 32
#define MT 2048
#define CD 512
#define NSLOT 16
#define NTOKENS 65536
#define SCALE -1.4285714285714286f

typedef short s16x8 __attribute__((ext_vector_type(8)));
typedef float f32x4 __attribute__((ext_vector_type(4)));

__device__ __forceinline__ float bf2f(unsigned short u) {
  return __uint_as_float(((unsigned)u) << 16);
}
__device__ __forceinline__ unsigned short f2bf(float f) {
  unsigned u = __float_as_uint(f);
  unsigned r = (u + 0x7fffu + ((u >> 16) & 1u)) >> 16;
  return (unsigned short)r;
}

// K1: L2-normalize rows of [NTOKENS, 512] fp32 -> bf16. One wave per row.
__global__ __launch_bounds__(256) void k_norm(const float* __restrict__ in,
                                              unsigned short* __restrict__ out) {
  int wid = threadIdx.x >> 6, lane = threadIdx.x & 63;
  long row = (long)blockIdx.x * 4 + wid;
  const float4* src = reinterpret_cast<const float4*>(in + row * CD);
  float4 v0 = src[lane];
  float4 v1 = src[64 + lane];
  float ss = v0.x * v0.x + v0.y * v0.y + v0.z * v0.z + v0.w * v0.w +
             v1.x * v1.x + v1.y * v1.y + v1.z * v1.z + v1.w * v1.w;
#pragma unroll
  for (int off = 32; off; off >>= 1) ss += __shfl_xor(ss, off);
  float rn = 1.0f / fmaxf(sqrtf(ss), 1e-12f);
  ushort4 o0, o1;
  o0.x = f2bf(v0.x * rn); o0.y = f2bf(v0.y * rn);
  o0.z = f2bf(v0.z * rn); o0.w = f2bf(v0.w * rn);
  o1.x = f2bf(v1.x * rn); o1.y = f2bf(v1.y * rn);
  o1.z = f2bf(v1.z * rn); o1.w = f2bf(v1.w * rn);
  ushort4* dst = reinterpret_cast<ushort4*>(out + row * CD);
  dst[lane] = o0;
  dst[64 + lane] = o1;
}

// K2: argmax over slot dim + per-(group,slot) histogram
__global__ __launch_bounds__(256) void k_grp(const float* __restrict__ masks,
                                             int* __restrict__ grp, int* __restrict__ cnt) {
  int t = blockIdx.x * 256 + threadIdx.x;  // t < 65536
  int bt = t >> 10, n = t & 1023;
  const float* p = masks + (size_t)bt * NSLOT * 1024 + n;
  float bv = p[0];
  int bs = 0;
#pragma unroll
  for (int s = 1; s < NSLOT; ++s) {
    float v = p[(size_t)s * 1024];
    if (v > bv) { bv = v; bs = s; }
  }
  grp[t] = bs;
  atomicAdd(&cnt[(t >> 11) * NSLOT + bs], 1);
}

// K3: fcsum[g][s][c] = sum of normalized fc rows with grp==s
__global__ __launch_bounds__(256) void k_fcsum(const unsigned short* __restrict__ fcb,
                                               const int* __restrict__ grp,
                                               float* __restrict__ fcsum) {
  __shared__ int gsh[MT];
  int g = blockIdx.x >> 1;
  int c = (blockIdx.x & 1) * 256 + threadIdx.x;
  for (int i = threadIdx.x; i < MT; i += 256) gsh[i] = grp[g * MT + i];
  __syncthreads();
  float acc[NSLOT];
#pragma unroll
  for (int s = 0; s < NSLOT; ++s) acc[s] = 0.f;
  const unsigned short* base = fcb + (size_t)g * MT * CD + c;
  for (int n = 0; n < MT; ++n) {
    float v = bf2f(base[(size_t)n * CD]);
    int gs = gsh[n];
#pragma unroll
    for (int s = 0; s < NSLOT; ++s) acc[s] += (gs == s) ? v : 0.f;
  }
#pragma unroll
  for (int s = 0; s < NSLOT; ++s) fcsum[((size_t)g * NSLOT + s) * CD + c] = acc[s];
}

// K4: per block (g, row-tile of 128): loop all 2048 cols, MFMA logits, accumulate sum(exp)
#define BM 128
#define BN 128
#define BK 64
#define LDP 72  // padded LDS row stride (elems): 144B -> +1 16B-chunk shift per row

__global__ __launch_bounds__(256, 2) void k_pair(const unsigned short* __restrict__ ftb,
                                                 const unsigned short* __restrict__ fcb,
                                                 float* __restrict__ sexp_out) {
  __shared__ unsigned short lA[BM * LDP];
  __shared__ unsigned short lB[BN * LDP];
  __shared__ float lrows[BM];

  const int g = blockIdx.x >> 4;
  const int r0 = (blockIdx.x & 15) * BM;
  const int tid = threadIdx.x;
  const int lane = tid & 63;
  const int wid = tid >> 6;
  const int wm = wid >> 1, wn = wid & 1;
  const int frow = lane & 15;
  const int fko = (lane >> 4) * 8;

  const unsigned short* Abase = ftb + (size_t)g * MT * CD;
  const unsigned short* Bbase = fcb + (size_t)g * MT * CD;

  float sexp_loc[4][4];
#pragma unroll
  for (int i = 0; i < 4; ++i)
#pragma unroll
    for (int j = 0; j < 4; ++j) sexp_loc[i][j] = 0.f;

  for (int n0 = 0; n0 < MT; n0 += BN) {
    f32x4 acc[4][4];
#pragma unroll
    for (int mi = 0; mi < 4; ++mi)
#pragma unroll
      for (int ni = 0; ni < 4; ++ni) acc[mi][ni] = (f32x4){0.f, 0.f, 0.f, 0.f};

    for (int kk = 0; kk < CD; kk += BK) {
      __syncthreads();
#pragma unroll
      for (int p = 0; p < 4; ++p) {
        int idx = (p * 256 + tid) * 8;
        int r = idx >> 6, k = idx & 63;
        *(s16x8*)(&lA[r * LDP + k]) =
            *(const s16x8*)(Abase + (size_t)(r0 + r) * CD + kk + k);
      }
#pragma unroll
      for (int p = 0; p < 4; ++p) {
        int idx = (p * 256 + tid) * 8;
        int r = idx >> 6, k = idx & 63;
        *(s16x8*)(&lB[r * LDP + k]) =
            *(const s16x8*)(Bbase + (size_t)(n0 + r) * CD + kk + k);
      }
      __syncthreads();
#pragma unroll
      for (int ks = 0; ks < 2; ++ks) {
        s16x8 af[4], bfv[4];
#pragma unroll
        for (int mi = 0; mi < 4; ++mi)
          af[mi] = *(const s16x8*)(&lA[(wm * 64 + mi * 16 + frow) * LDP + ks * 32 + fko]);
#pragma unroll
        for (int ni = 0; ni < 4; ++ni)
          bfv[ni] = *(const s16x8*)(&lB[(wn * 64 + ni * 16 + frow) * LDP + ks * 32 + fko]);
#pragma unroll
        for (int mi = 0; mi < 4; ++mi)
#pragma unroll
          for (int ni = 0; ni < 4; ++ni)
            acc[mi][ni] =
                __builtin_amdgcn_mfma_f32_16x16x32_bf16(af[mi], bfv[ni], acc[mi][ni], 0, 0, 0);
      }
    }
    // epilogue: logits bounded by +-10.2 -> exp without max subtraction is safe
#pragma unroll
    for (int mi = 0; mi < 4; ++mi)
#pragma unroll
      for (int r = 0; r < 4; ++r) {
        float e = 0.f;
#pragma unroll
        for (int ni = 0; ni < 4; ++ni) e += __expf(acc[mi][ni][r] * 10.0f);
        sexp_loc[mi][r] += e;
      }
  }
  // reduce over the 16 column-lanes (C/D layout: col=lane&15, row=(lane>>4)*4+reg)
#pragma unroll
  for (int mi = 0; mi < 4; ++mi)
#pragma unroll
    for (int r = 0; r < 4; ++r) {
      float v = sexp_loc[mi][r];
      v += __shfl_xor(v, 1);
      v += __shfl_xor(v, 2);
      v += __shfl_xor(v, 4);
      v += __shfl_xor(v, 8);
      sexp_loc[mi][r] = v;
    }
  __syncthreads();
  if (wn == 0 && (lane & 15) == 0) {
#pragma unroll
    for (int mi = 0; mi < 4; ++mi)
#pragma unroll
      for (int r = 0; r < 4; ++r)
        lrows[wm * 64 + mi * 16 + (lane >> 4) * 4 + r] = sexp_loc[mi][r];
  }
  __syncthreads();
  if (wn == 1 && (lane & 15) == 0) {
#pragma unroll
    for (int mi = 0; mi < 4; ++mi)
#pragma unroll
      for (int r = 0; r < 4; ++r)
        lrows[wm * 64 + mi * 16 + (lane >> 4) * 4 + r] += sexp_loc[mi][r];
  }
  __syncthreads();
  if (tid < BM) sexp_out[(size_t)g * MT + r0 + tid] = lrows[tid];
}

// K5: per-token loss using diag dot, slot-sum dot, lse, counts
__global__ __launch_bounds__(256) void k_loss(const unsigned short* __restrict__ ftb,
                                              const unsigned short* __restrict__ fcb,
                                              const float* __restrict__ fcsum,
                                              const int* __restrict__ grp,
                                              const int* __restrict__ cnt,
                                              const float* __restrict__ sexp,
                                              float* __restrict__ loss) {
  int wid = threadIdx.x >> 6, lane = threadIdx.x & 63;
  for (int t = blockIdx.x * 4 + wid; t < NTOKENS; t += 4096) {
    int g = t >> 11;
    const unsigned short* fr = ftb + (size_t)t * CD;
    const unsigned short* cr = fcb + (size_t)t * CD;
    int gs = grp[t];
    const float* sr = fcsum + ((size_t)g * NSLOT + gs) * CD;
    float d1 = 0.f, d2 = 0.f;
#pragma unroll
    for (int j = 0; j < 8; ++j) {
      int c = lane + j * 64;
      float fv = bf2f(fr[c]);
      d1 += fv * bf2f(cr[c]);
      d2 += fv * sr[c];
    }
#pragma unroll
    for (int off = 32; off; off >>= 1) {
      d1 += __shfl_xor(d1, off);
      d2 += __shfl_xor(d2, off);
    }
    if (lane == 0) {
      float lse = __logf(sexp[t]);
      float cm = (float)cnt[g * NSLOT + gs];
      float semi = SCALE * (d2 * 10.0f / cm - lse);
      float pos = SCALE * (d1 * 10.0f - lse);
      loss[t] = 0.5f * (semi + pos);
    }
  }
}

// K6: final mean
__global__ __launch_bounds__(256) void k_reduce(const float* __restrict__ loss,
                                                float* __restrict__ out) {
  __shared__ float sh[4];
  float s = 0.f;
  for (int i = threadIdx.x; i < NTOKENS; i += 256) s += loss[i];
#pragma unroll
  for (int off = 32; off; off >>= 1) s += __shfl_xor(s, off);
  if ((threadIdx.x & 63) == 0) sh[threadIdx.x >> 6] = s;
  __syncthreads();
  if (threadIdx.x == 0) out[0] = (sh[0] + sh[1] + sh[2] + sh[3]) * (1.0f / NTOKENS);
}

extern "C" void kernel_launch(void* const* d_in, const int* in_sizes, int n_in,
                              void* d_out, int out_size, void* d_ws, size_t ws_size,
                              hipStream_t stream) {
  const float* ft = (const float*)d_in[0];
  const float* fc = (const float*)d_in[1];
  const float* masks = (const float*)d_in[2];
  char* ws = (char*)d_ws;

  // workspace layout (bytes)
  unsigned short* ftb = (unsigned short*)(ws);                   // 67108864
  unsigned short* fcb = (unsigned short*)(ws + 67108864);        // 67108864
  int* grp = (int*)(ws + 134217728);                             // 262144
  int* cnt = (int*)(ws + 134479872);                             // 2048
  float* fcsum = (float*)(ws + 134481920);                       // 1048576
  float* sexp = (float*)(ws + 135530496);                        // 262144
  float* loss = (float*)(ws + 135792640);                        // 262144
  float* out = (float*)d_out;

  hipMemsetAsync(cnt, 0, GN * NSLOT * sizeof(int), stream);
  k_norm<<<NTOKENS / 4, 256, 0, stream>>>(ft, ftb);
  k_norm<<<NTOKENS / 4, 256, 0, stream>>>(fc, fcb);
  k_grp<<<NTOKENS / 256, 256, 0, stream>>>(masks, grp, cnt);
  k_fcsum<<<GN * 2, 256, 0, stream>>>(fcb, grp, fcsum);
  k_pair<<<GN * (MT / BM), 256, 0, stream>>>(ftb, fcb, sexp);
  k_loss<<<1024, 256, 0, stream>>>(ftb, fcb, fcsum, grp, cnt, sexp, loss);
  k_reduce<<<1, 256, 0, stream>>>(loss, out);
}

// Round 2
// 648.700 us; speedup vs baseline: 1.6894x; 1.6894x over previous
//
#include <hip/hip_runtime.h>

#define GN 32
#define MT 2048
#define CD 512
#define NSLOT 16
#define NTOKENS 65536
#define SCALE -1.4285714285714286f

typedef short s16x8 __attribute__((ext_vector_type(8)));
typedef float f32x4 __attribute__((ext_vector_type(4)));

__device__ __forceinline__ float bf2f(unsigned short u) {
  return __uint_as_float(((unsigned)u) << 16);
}
__device__ __forceinline__ unsigned short f2bf(float f) {
  unsigned u = __float_as_uint(f);
  unsigned r = (u + 0x7fffu + ((u >> 16) & 1u)) >> 16;
  return (unsigned short)r;
}

// K1: L2-normalize rows of [NTOKENS, 512] fp32 -> bf16. One wave per row.
__global__ __launch_bounds__(256) void k_norm(const float* __restrict__ in,
                                              unsigned short* __restrict__ out) {
  int wid = threadIdx.x >> 6, lane = threadIdx.x & 63;
  long row = (long)blockIdx.x * 4 + wid;
  const float4* src = reinterpret_cast<const float4*>(in + row * CD);
  float4 v0 = src[lane];
  float4 v1 = src[64 + lane];
  float ss = v0.x * v0.x + v0.y * v0.y + v0.z * v0.z + v0.w * v0.w +
             v1.x * v1.x + v1.y * v1.y + v1.z * v1.z + v1.w * v1.w;
#pragma unroll
  for (int off = 32; off; off >>= 1) ss += __shfl_xor(ss, off);
  float rn = 1.0f / fmaxf(sqrtf(ss), 1e-12f);
  ushort4 o0, o1;
  o0.x = f2bf(v0.x * rn); o0.y = f2bf(v0.y * rn);
  o0.z = f2bf(v0.z * rn); o0.w = f2bf(v0.w * rn);
  o1.x = f2bf(v1.x * rn); o1.y = f2bf(v1.y * rn);
  o1.z = f2bf(v1.z * rn); o1.w = f2bf(v1.w * rn);
  ushort4* dst = reinterpret_cast<ushort4*>(out + row * CD);
  dst[lane] = o0;
  dst[64 + lane] = o1;
}

// K2: argmax over slot dim + per-(group,slot) histogram
__global__ __launch_bounds__(256) void k_grp(const float* __restrict__ masks,
                                             int* __restrict__ grp, int* __restrict__ cnt) {
  int t = blockIdx.x * 256 + threadIdx.x;  // t < 65536
  int bt = t >> 10, n = t & 1023;
  const float* p = masks + (size_t)bt * NSLOT * 1024 + n;
  float bv = p[0];
  int bs = 0;
#pragma unroll
  for (int s = 1; s < NSLOT; ++s) {
    float v = p[(size_t)s * 1024];
    if (v > bv) { bv = v; bs = s; }
  }
  grp[t] = bs;
  atomicAdd(&cnt[(t >> 11) * NSLOT + bs], 1);
}

// K3a: partial fcsum over row-chunks. block = (g, chunk of 128 rows); thread owns cols {2t, 2t+1}
#define FCH 128
#define NCH (MT / FCH)  // 16
__global__ __launch_bounds__(256) void k_fcsum_part(const unsigned short* __restrict__ fcb,
                                                    const int* __restrict__ grp,
                                                    float* __restrict__ part) {
  __shared__ int gsh[FCH];
  int g = blockIdx.x >> 4;
  int ch = blockIdx.x & 15;
  int t = threadIdx.x;
  if (t < FCH) gsh[t] = grp[g * MT + ch * FCH + t];
  __syncthreads();
  float ax[NSLOT], ay[NSLOT];
#pragma unroll
  for (int s = 0; s < NSLOT; ++s) { ax[s] = 0.f; ay[s] = 0.f; }
  const unsigned short* base = fcb + ((size_t)g * MT + ch * FCH) * CD + 2 * t;
  for (int n = 0; n < FCH; ++n) {
    unsigned u = *(const unsigned*)(base + (size_t)n * CD);
    float v0 = bf2f((unsigned short)(u & 0xffff));
    float v1 = bf2f((unsigned short)(u >> 16));
    int gs = gsh[n];
#pragma unroll
    for (int s = 0; s < NSLOT; ++s) {
      bool m = (gs == s);
      ax[s] += m ? v0 : 0.f;
      ay[s] += m ? v1 : 0.f;
    }
  }
  float* dst = part + ((size_t)(g * NCH + ch) * NSLOT) * CD + 2 * t;
#pragma unroll
  for (int s = 0; s < NSLOT; ++s) {
    dst[(size_t)s * CD] = ax[s];
    dst[(size_t)s * CD + 1] = ay[s];
  }
}

// K3b: reduce partials over the 16 chunks
__global__ __launch_bounds__(256) void k_fcsum_red(const float* __restrict__ part,
                                                   float* __restrict__ fcsum) {
  int idx = blockIdx.x * 256 + threadIdx.x;  // < GN*NSLOT*CD = 262144
  int g = idx >> 13;
  int sc = idx & 8191;
  float s = 0.f;
#pragma unroll
  for (int ch = 0; ch < NCH; ++ch)
    s += part[((size_t)(g * NCH + ch) * NSLOT) * CD + sc];
  fcsum[idx] = s;
}

// K3 fallback (slow, no extra ws): original column-accumulate version
__global__ __launch_bounds__(256) void k_fcsum(const unsigned short* __restrict__ fcb,
                                               const int* __restrict__ grp,
                                               float* __restrict__ fcsum) {
  __shared__ int gsh[MT];
  int g = blockIdx.x >> 1;
  int c = (blockIdx.x & 1) * 256 + threadIdx.x;
  for (int i = threadIdx.x; i < MT; i += 256) gsh[i] = grp[g * MT + i];
  __syncthreads();
  float acc[NSLOT];
#pragma unroll
  for (int s = 0; s < NSLOT; ++s) acc[s] = 0.f;
  const unsigned short* base = fcb + (size_t)g * MT * CD + c;
  for (int n = 0; n < MT; ++n) {
    float v = bf2f(base[(size_t)n * CD]);
    int gs = gsh[n];
#pragma unroll
    for (int s = 0; s < NSLOT; ++s) acc[s] += (gs == s) ? v : 0.f;
  }
#pragma unroll
  for (int s = 0; s < NSLOT; ++s) fcsum[((size_t)g * NSLOT + s) * CD + c] = acc[s];
}

// K4: per block (g, row-tile of 128): loop all 2048 cols, MFMA logits, accumulate sum(exp)
#define BM 128
#define BN 128
#define BK 64
#define LDP 72  // padded LDS row stride (elems)

__global__ __launch_bounds__(256, 2) void k_pair(const unsigned short* __restrict__ ftb,
                                                 const unsigned short* __restrict__ fcb,
                                                 float* __restrict__ sexp_out) {
  __shared__ unsigned short lA[BM * LDP];
  __shared__ unsigned short lB[BN * LDP];
  __shared__ float lrows[BM];

  const int g = blockIdx.x >> 4;
  const int r0 = (blockIdx.x & 15) * BM;
  const int tid = threadIdx.x;
  const int lane = tid & 63;
  const int wid = tid >> 6;
  const int wm = wid >> 1, wn = wid & 1;
  const int frow = lane & 15;
  const int fko = (lane >> 4) * 8;

  const unsigned short* Abase = ftb + (size_t)g * MT * CD;
  const unsigned short* Bbase = fcb + (size_t)g * MT * CD;

  float sexp_loc[4][4];
#pragma unroll
  for (int i = 0; i < 4; ++i)
#pragma unroll
    for (int j = 0; j < 4; ++j) sexp_loc[i][j] = 0.f;

  for (int n0 = 0; n0 < MT; n0 += BN) {
    f32x4 acc[4][4];
#pragma unroll
    for (int mi = 0; mi < 4; ++mi)
#pragma unroll
      for (int ni = 0; ni < 4; ++ni) acc[mi][ni] = (f32x4){0.f, 0.f, 0.f, 0.f};

    for (int kk = 0; kk < CD; kk += BK) {
      __syncthreads();
#pragma unroll
      for (int p = 0; p < 4; ++p) {
        int idx = (p * 256 + tid) * 8;
        int r = idx >> 6, k = idx & 63;
        *(s16x8*)(&lA[r * LDP + k]) =
            *(const s16x8*)(Abase + (size_t)(r0 + r) * CD + kk + k);
      }
#pragma unroll
      for (int p = 0; p < 4; ++p) {
        int idx = (p * 256 + tid) * 8;
        int r = idx >> 6, k = idx & 63;
        *(s16x8*)(&lB[r * LDP + k]) =
            *(const s16x8*)(Bbase + (size_t)(n0 + r) * CD + kk + k);
      }
      __syncthreads();
#pragma unroll
      for (int ks = 0; ks < 2; ++ks) {
        s16x8 af[4], bfv[4];
#pragma unroll
        for (int mi = 0; mi < 4; ++mi)
          af[mi] = *(const s16x8*)(&lA[(wm * 64 + mi * 16 + frow) * LDP + ks * 32 + fko]);
#pragma unroll
        for (int ni = 0; ni < 4; ++ni)
          bfv[ni] = *(const s16x8*)(&lB[(wn * 64 + ni * 16 + frow) * LDP + ks * 32 + fko]);
#pragma unroll
        for (int mi = 0; mi < 4; ++mi)
#pragma unroll
          for (int ni = 0; ni < 4; ++ni)
            acc[mi][ni] =
                __builtin_amdgcn_mfma_f32_16x16x32_bf16(af[mi], bfv[ni], acc[mi][ni], 0, 0, 0);
      }
    }
#pragma unroll
    for (int mi = 0; mi < 4; ++mi)
#pragma unroll
      for (int r = 0; r < 4; ++r) {
        float e = 0.f;
#pragma unroll
        for (int ni = 0; ni < 4; ++ni) e += __expf(acc[mi][ni][r] * 10.0f);
        sexp_loc[mi][r] += e;
      }
  }
#pragma unroll
  for (int mi = 0; mi < 4; ++mi)
#pragma unroll
    for (int r = 0; r < 4; ++r) {
      float v = sexp_loc[mi][r];
      v += __shfl_xor(v, 1);
      v += __shfl_xor(v, 2);
      v += __shfl_xor(v, 4);
      v += __shfl_xor(v, 8);
      sexp_loc[mi][r] = v;
    }
  __syncthreads();
  if (wn == 0 && (lane & 15) == 0) {
#pragma unroll
    for (int mi = 0; mi < 4; ++mi)
#pragma unroll
      for (int r = 0; r < 4; ++r)
        lrows[wm * 64 + mi * 16 + (lane >> 4) * 4 + r] = sexp_loc[mi][r];
  }
  __syncthreads();
  if (wn == 1 && (lane & 15) == 0) {
#pragma unroll
    for (int mi = 0; mi < 4; ++mi)
#pragma unroll
      for (int r = 0; r < 4; ++r)
        lrows[wm * 64 + mi * 16 + (lane >> 4) * 4 + r] += sexp_loc[mi][r];
  }
  __syncthreads();
  if (tid < BM) sexp_out[(size_t)g * MT + r0 + tid] = lrows[tid];
}

// K5: per-token loss using diag dot, slot-sum dot, lse, counts
__global__ __launch_bounds__(256) void k_loss(const unsigned short* __restrict__ ftb,
                                              const unsigned short* __restrict__ fcb,
                                              const float* __restrict__ fcsum,
                                              const int* __restrict__ grp,
                                              const int* __restrict__ cnt,
                                              const float* __restrict__ sexp,
                                              float* __restrict__ loss) {
  int wid = threadIdx.x >> 6, lane = threadIdx.x & 63;
  for (int t = blockIdx.x * 4 + wid; t < NTOKENS; t += 4096) {
    int g = t >> 11;
    const unsigned short* fr = ftb + (size_t)t * CD;
    const unsigned short* cr = fcb + (size_t)t * CD;
    int gs = grp[t];
    const float* sr = fcsum + ((size_t)g * NSLOT + gs) * CD;
    float d1 = 0.f, d2 = 0.f;
#pragma unroll
    for (int j = 0; j < 8; ++j) {
      int c = lane + j * 64;
      float fv = bf2f(fr[c]);
      d1 += fv * bf2f(cr[c]);
      d2 += fv * sr[c];
    }
#pragma unroll
    for (int off = 32; off; off >>= 1) {
      d1 += __shfl_xor(d1, off);
      d2 += __shfl_xor(d2, off);
    }
    if (lane == 0) {
      float lse = __logf(sexp[t]);
      float cm = (float)cnt[g * NSLOT + gs];
      float semi = SCALE * (d2 * 10.0f / cm - lse);
      float pos = SCALE * (d1 * 10.0f - lse);
      loss[t] = 0.5f * (semi + pos);
    }
  }
}

// K6: final mean
__global__ __launch_bounds__(256) void k_reduce(const float* __restrict__ loss,
                                                float* __restrict__ out) {
  __shared__ float sh[4];
  float s = 0.f;
  for (int i = threadIdx.x; i < NTOKENS; i += 256) s += loss[i];
#pragma unroll
  for (int off = 32; off; off >>= 1) s += __shfl_xor(s, off);
  if ((threadIdx.x & 63) == 0) sh[threadIdx.x >> 6] = s;
  __syncthreads();
  if (threadIdx.x == 0) out[0] = (sh[0] + sh[1] + sh[2] + sh[3]) * (1.0f / NTOKENS);
}

extern "C" void kernel_launch(void* const* d_in, const int* in_sizes, int n_in,
                              void* d_out, int out_size, void* d_ws, size_t ws_size,
                              hipStream_t stream) {
  const float* ft = (const float*)d_in[0];
  const float* fc = (const float*)d_in[1];
  const float* masks = (const float*)d_in[2];
  char* ws = (char*)d_ws;

  // workspace layout (bytes)
  unsigned short* ftb = (unsigned short*)(ws);                   // 67108864
  unsigned short* fcb = (unsigned short*)(ws + 67108864);        // 67108864
  int* grp = (int*)(ws + 134217728);                             // 262144
  int* cnt = (int*)(ws + 134479872);                             // 2048
  float* fcsum = (float*)(ws + 134481920);                       // 1048576
  float* sexp = (float*)(ws + 135530496);                        // 262144
  float* loss = (float*)(ws + 135792640);                        // 262144
  float* part = (float*)(ws + 136054784);                        // 16777216
  const size_t WS_NEED_PART = 136054784UL + 16777216UL;
  float* out = (float*)d_out;

  hipMemsetAsync(cnt, 0, GN * NSLOT * sizeof(int), stream);
  k_norm<<<NTOKENS / 4, 256, 0, stream>>>(ft, ftb);
  k_norm<<<NTOKENS / 4, 256, 0, stream>>>(fc, fcb);
  k_grp<<<NTOKENS / 256, 256, 0, stream>>>(masks, grp, cnt);
  if (ws_size >= WS_NEED_PART) {
    k_fcsum_part<<<GN * NCH, 256, 0, stream>>>(fcb, grp, part);
    k_fcsum_red<<<GN * NSLOT * CD / 256, 256, 0, stream>>>(part, fcsum);
  } else {
    k_fcsum<<<GN * 2, 256, 0, stream>>>(fcb, grp, fcsum);
  }
  k_pair<<<GN * (MT / BM), 256, 0, stream>>>(ftb, fcb, sexp);
  k_loss<<<1024, 256, 0, stream>>>(ftb, fcb, fcsum, grp, cnt, sexp, loss);
  k_reduce<<<1, 256, 0, stream>>>(loss, out);
}

// Round 3
// 494.412 us; speedup vs baseline: 2.2165x; 1.3121x over previous
//
#include <hip/hip_runtime.h>

#define GN 32
#define MT 2048
#define CD 512
#define NSLOT 16
#define NTOKENS 65536
#define SCALE -1.4285714285714286f

typedef short s16x8 __attribute__((ext_vector_type(8)));
typedef float f32x4 __attribute__((ext_vector_type(4)));

__device__ __forceinline__ float bf2f(unsigned short u) {
  return __uint_as_float(((unsigned)u) << 16);
}
__device__ __forceinline__ unsigned short f2bf(float f) {
  unsigned u = __float_as_uint(f);
  unsigned r = (u + 0x7fffu + ((u >> 16) & 1u)) >> 16;
  return (unsigned short)r;
}

typedef __attribute__((address_space(3))) unsigned lds_u32_t;
typedef __attribute__((address_space(1))) const unsigned glb_u32_t;

__device__ __forceinline__ void gload16(const unsigned short* g, unsigned short* l) {
  __builtin_amdgcn_global_load_lds((glb_u32_t*)g, (lds_u32_t*)l, 16, 0, 0);
}

// K1: L2-normalize rows of [NTOKENS, 512] fp32 -> bf16. One wave per row.
__global__ __launch_bounds__(256) void k_norm(const float* __restrict__ in,
                                              unsigned short* __restrict__ out) {
  int wid = threadIdx.x >> 6, lane = threadIdx.x & 63;
  long row = (long)blockIdx.x * 4 + wid;
  const float4* src = reinterpret_cast<const float4*>(in + row * CD);
  float4 v0 = src[lane];
  float4 v1 = src[64 + lane];
  float ss = v0.x * v0.x + v0.y * v0.y + v0.z * v0.z + v0.w * v0.w +
             v1.x * v1.x + v1.y * v1.y + v1.z * v1.z + v1.w * v1.w;
#pragma unroll
  for (int off = 32; off; off >>= 1) ss += __shfl_xor(ss, off);
  float rn = 1.0f / fmaxf(sqrtf(ss), 1e-12f);
  ushort4 o0, o1;
  o0.x = f2bf(v0.x * rn); o0.y = f2bf(v0.y * rn);
  o0.z = f2bf(v0.z * rn); o0.w = f2bf(v0.w * rn);
  o1.x = f2bf(v1.x * rn); o1.y = f2bf(v1.y * rn);
  o1.z = f2bf(v1.z * rn); o1.w = f2bf(v1.w * rn);
  ushort4* dst = reinterpret_cast<ushort4*>(out + row * CD);
  dst[lane] = o0;
  dst[64 + lane] = o1;
}

// K2: argmax over slot dim + per-(group,slot) histogram
__global__ __launch_bounds__(256) void k_grp(const float* __restrict__ masks,
                                             int* __restrict__ grp, int* __restrict__ cnt) {
  int t = blockIdx.x * 256 + threadIdx.x;  // t < 65536
  int bt = t >> 10, n = t & 1023;
  const float* p = masks + (size_t)bt * NSLOT * 1024 + n;
  float bv = p[0];
  int bs = 0;
#pragma unroll
  for (int s = 1; s < NSLOT; ++s) {
    float v = p[(size_t)s * 1024];
    if (v > bv) { bv = v; bs = s; }
  }
  grp[t] = bs;
  atomicAdd(&cnt[(t >> 11) * NSLOT + bs], 1);
}

// K3a: partial fcsum over row-chunks. block = (g, chunk of 256 rows); thread owns cols {2t, 2t+1}
#define FCH 256
#define NCH (MT / FCH)  // 8
__global__ __launch_bounds__(256) void k_fcsum_part(const unsigned short* __restrict__ fcb,
                                                    const int* __restrict__ grp,
                                                    float* __restrict__ part) {
  __shared__ int gsh[FCH];
  int g = blockIdx.x >> 3;
  int ch = blockIdx.x & 7;
  int t = threadIdx.x;
  gsh[t] = grp[g * MT + ch * FCH + t];
  __syncthreads();
  float ax[NSLOT], ay[NSLOT];
#pragma unroll
  for (int s = 0; s < NSLOT; ++s) { ax[s] = 0.f; ay[s] = 0.f; }
  const unsigned short* base = fcb + ((size_t)g * MT + ch * FCH) * CD + 2 * t;
  for (int n = 0; n < FCH; ++n) {
    unsigned u = *(const unsigned*)(base + (size_t)n * CD);
    float v0 = bf2f((unsigned short)(u & 0xffff));
    float v1 = bf2f((unsigned short)(u >> 16));
    int gs = gsh[n];
#pragma unroll
    for (int s = 0; s < NSLOT; ++s) {
      bool m = (gs == s);
      ax[s] += m ? v0 : 0.f;
      ay[s] += m ? v1 : 0.f;
    }
  }
  float* dst = part + ((size_t)(g * NCH + ch) * NSLOT) * CD + 2 * t;
#pragma unroll
  for (int s = 0; s < NSLOT; ++s) {
    dst[(size_t)s * CD] = ax[s];
    dst[(size_t)s * CD + 1] = ay[s];
  }
}

// K3b: reduce partials over the chunks
__global__ __launch_bounds__(256) void k_fcsum_red(const float* __restrict__ part,
                                                   float* __restrict__ fcsum) {
  int idx = blockIdx.x * 256 + threadIdx.x;  // < GN*NSLOT*CD = 262144
  int g = idx >> 13;
  int sc = idx & 8191;
  float s = 0.f;
#pragma unroll
  for (int ch = 0; ch < NCH; ++ch)
    s += part[((size_t)(g * NCH + ch) * NSLOT) * CD + sc];
  fcsum[idx] = s;
}

// K3 fallback (slow, no extra ws): original column-accumulate version
__global__ __launch_bounds__(256) void k_fcsum(const unsigned short* __restrict__ fcb,
                                               const int* __restrict__ grp,
                                               float* __restrict__ fcsum) {
  __shared__ int gsh[MT];
  int g = blockIdx.x >> 1;
  int c = (blockIdx.x & 1) * 256 + threadIdx.x;
  for (int i = threadIdx.x; i < MT; i += 256) gsh[i] = grp[g * MT + i];
  __syncthreads();
  float acc[NSLOT];
#pragma unroll
  for (int s = 0; s < NSLOT; ++s) acc[s] = 0.f;
  const unsigned short* base = fcb + (size_t)g * MT * CD + c;
  for (int n = 0; n < MT; ++n) {
    float v = bf2f(base[(size_t)n * CD]);
    int gs = gsh[n];
#pragma unroll
    for (int s = 0; s < NSLOT; ++s) acc[s] += (gs == s) ? v : 0.f;
  }
#pragma unroll
  for (int s = 0; s < NSLOT; ++s) fcsum[((size_t)g * NSLOT + s) * CD + c] = acc[s];
}

// K4: m97-structure pair kernel.
// Block = (g, row-tile of 128, N-half). Loops its 1024 cols in 128-col tiles,
// K-inner with global_load_lds staging + XOR-swizzled LDS, MFMA 16x16x32,
// accumulates per-row sum(exp(logit)) into sexp_part[ns].
#define BM 128
#define BN 128
#define BK 64
#define NSPAN 1024

__global__ __launch_bounds__(256, 4) void k_pair(const unsigned short* __restrict__ ftb,
                                                 const unsigned short* __restrict__ fcb,
                                                 float* __restrict__ sexp_part) {
  __shared__ unsigned short lA[BM * BK];
  __shared__ unsigned short lB[BN * BK];
  __shared__ float lrows[BM];

  // XCD swizzle: all 32 blocks of a group land on the same XCD (b%8 heuristic)
  const int b = blockIdx.x;
  const int xcd = b & 7;
  const int u = b >> 3;                 // 0..127
  const int g = (u >> 5) * 8 + xcd;     // 4 groups per XCD
  const int v = u & 31;
  const int rt = v >> 1;                // 16 row tiles
  const int ns = v & 1;                 // N half
  const int r0 = rt * BM;
  const int c0 = ns * NSPAN;

  const int tid = threadIdx.x;
  const int lane = tid & 63;
  const int wid = tid >> 6;
  const int wm = wid >> 1, wn = wid & 1;
  const int frow = lane & 15;

  const unsigned short* Abase = ftb + (size_t)g * MT * CD;
  const unsigned short* Bbase = fcb + (size_t)g * MT * CD;

  // staging: per gload instr, lane covers (row = lane>>3, chunk16B = lane&7);
  // source chunk pre-swizzled: chunk ^ (row&7)  (row&7 == lane>>3 here)
  const int aoff = (lane >> 3) * CD + (((lane & 7) ^ (lane >> 3)) << 3);

  // frag-read LDS byte addrs (swizzled): row = frow (+uniform), chunk = ks*4 + (lane>>4)
  const int f7 = frow & 7;
  const int ch0 = lane >> 4;
  const int adA0 = wm * 8192 + frow * 128 + ((ch0 ^ f7) << 4);
  const int adA1 = wm * 8192 + frow * 128 + (((4 | ch0) ^ f7) << 4);
  const int adB0 = wn * 8192 + frow * 128 + ((ch0 ^ f7) << 4);
  const int adB1 = wn * 8192 + frow * 128 + (((4 | ch0) ^ f7) << 4);
  const char* LAc = (const char*)lA;
  const char* LBc = (const char*)lB;

  float sexp_loc[4][4];
#pragma unroll
  for (int i = 0; i < 4; ++i)
#pragma unroll
    for (int j = 0; j < 4; ++j) sexp_loc[i][j] = 0.f;

  for (int n0 = c0; n0 < c0 + NSPAN; n0 += BN) {
    f32x4 acc[4][4];
#pragma unroll
    for (int mi = 0; mi < 4; ++mi)
#pragma unroll
      for (int ni = 0; ni < 4; ++ni) acc[mi][ni] = (f32x4){0.f, 0.f, 0.f, 0.f};

    for (int kk = 0; kk < CD; kk += BK) {
      __syncthreads();  // prior tile's ds_reads complete before overwrite
      const unsigned short* pa = Abase + (size_t)(r0 + wid * 32) * CD + kk + aoff;
      const unsigned short* pb = Bbase + (size_t)(n0 + wid * 32) * CD + kk + aoff;
      unsigned short* da = &lA[wid * 32 * BK];
      unsigned short* db = &lB[wid * 32 * BK];
#pragma unroll
      for (int j = 0; j < 4; ++j) {
        gload16(pa + (size_t)(j * 8) * CD, da + j * 8 * BK);
        gload16(pb + (size_t)(j * 8) * CD, db + j * 8 * BK);
      }
      __syncthreads();  // compiler drains vmcnt before barrier
#pragma unroll
      for (int ks = 0; ks < 2; ++ks) {
        s16x8 af[4], bfv[4];
        const int aA = ks ? adA1 : adA0;
        const int aB = ks ? adB1 : adB0;
#pragma unroll
        for (int ni = 0; ni < 4; ++ni)
          bfv[ni] = *(const s16x8*)(LBc + aB + ni * 2048);
#pragma unroll
        for (int mi = 0; mi < 4; ++mi)
          af[mi] = *(const s16x8*)(LAc + aA + mi * 2048);
#pragma unroll
        for (int mi = 0; mi < 4; ++mi)
#pragma unroll
          for (int ni = 0; ni < 4; ++ni)
            acc[mi][ni] =
                __builtin_amdgcn_mfma_f32_16x16x32_bf16(af[mi], bfv[ni], acc[mi][ni], 0, 0, 0);
      }
    }
    // epilogue: logits bounded by +-10.2 -> exp without max subtraction is safe
#pragma unroll
    for (int mi = 0; mi < 4; ++mi)
#pragma unroll
      for (int r = 0; r < 4; ++r) {
        float e = 0.f;
#pragma unroll
        for (int ni = 0; ni < 4; ++ni) e += __expf(acc[mi][ni][r] * 10.0f);
        sexp_loc[mi][r] += e;
      }
  }
  // reduce over the 16 column-lanes (C/D layout: col=lane&15, row=(lane>>4)*4+reg)
#pragma unroll
  for (int mi = 0; mi < 4; ++mi)
#pragma unroll
    for (int r = 0; r < 4; ++r) {
      float v2 = sexp_loc[mi][r];
      v2 += __shfl_xor(v2, 1);
      v2 += __shfl_xor(v2, 2);
      v2 += __shfl_xor(v2, 4);
      v2 += __shfl_xor(v2, 8);
      sexp_loc[mi][r] = v2;
    }
  __syncthreads();
  if (wn == 0 && (lane & 15) == 0) {
#pragma unroll
    for (int mi = 0; mi < 4; ++mi)
#pragma unroll
      for (int r = 0; r < 4; ++r)
        lrows[wm * 64 + mi * 16 + (lane >> 4) * 4 + r] = sexp_loc[mi][r];
  }
  __syncthreads();
  if (wn == 1 && (lane & 15) == 0) {
#pragma unroll
    for (int mi = 0; mi < 4; ++mi)
#pragma unroll
      for (int r = 0; r < 4; ++r)
        lrows[wm * 64 + mi * 16 + (lane >> 4) * 4 + r] += sexp_loc[mi][r];
  }
  __syncthreads();
  if (tid < BM)
    sexp_part[((size_t)ns * GN + g) * MT + r0 + tid] = lrows[tid];
}

// K5: per-token loss using diag dot, slot-sum dot, lse (from 2 partials), counts
__global__ __launch_bounds__(256) void k_loss(const unsigned short* __restrict__ ftb,
                                              const unsigned short* __restrict__ fcb,
                                              const float* __restrict__ fcsum,
                                              const int* __restrict__ grp,
                                              const int* __restrict__ cnt,
                                              const float* __restrict__ sexp,
                                              float* __restrict__ loss) {
  int wid = threadIdx.x >> 6, lane = threadIdx.x & 63;
  for (int t = blockIdx.x * 4 + wid; t < NTOKENS; t += 4096) {
    int g = t >> 11;
    const unsigned short* fr = ftb + (size_t)t * CD;
    const unsigned short* cr = fcb + (size_t)t * CD;
    int gs = grp[t];
    const float* sr = fcsum + ((size_t)g * NSLOT + gs) * CD;
    float d1 = 0.f, d2 = 0.f;
#pragma unroll
    for (int j = 0; j < 8; ++j) {
      int c = lane + j * 64;
      float fv = bf2f(fr[c]);
      d1 += fv * bf2f(cr[c]);
      d2 += fv * sr[c];
    }
#pragma unroll
    for (int off = 32; off; off >>= 1) {
      d1 += __shfl_xor(d1, off);
      d2 += __shfl_xor(d2, off);
    }
    if (lane == 0) {
      float lse = __logf(sexp[t] + sexp[NTOKENS + t]);  // (g,m) flat == t
      float cm = (float)cnt[g * NSLOT + gs];
      float semi = SCALE * (d2 * 10.0f / cm - lse);
      float pos = SCALE * (d1 * 10.0f - lse);
      loss[t] = 0.5f * (semi + pos);
    }
  }
}

// K6: final mean
__global__ __launch_bounds__(256) void k_reduce(const float* __restrict__ loss,
                                                float* __restrict__ out) {
  __shared__ float sh[4];
  float s = 0.f;
  for (int i = threadIdx.x; i < NTOKENS; i += 256) s += loss[i];
#pragma unroll
  for (int off = 32; off; off >>= 1) s += __shfl_xor(s, off);
  if ((threadIdx.x & 63) == 0) sh[threadIdx.x >> 6] = s;
  __syncthreads();
  if (threadIdx.x == 0) out[0] = (sh[0] + sh[1] + sh[2] + sh[3]) * (1.0f / NTOKENS);
}

extern "C" void kernel_launch(void* const* d_in, const int* in_sizes, int n_in,
                              void* d_out, int out_size, void* d_ws, size_t ws_size,
                              hipStream_t stream) {
  const float* ft = (const float*)d_in[0];
  const float* fc = (const float*)d_in[1];
  const float* masks = (const float*)d_in[2];
  char* ws = (char*)d_ws;

  // workspace layout (bytes)
  unsigned short* ftb = (unsigned short*)(ws);                   // 67108864
  unsigned short* fcb = (unsigned short*)(ws + 67108864);        // 67108864
  int* grp = (int*)(ws + 134217728);                             // 262144
  int* cnt = (int*)(ws + 134479872);                             // 2048
  float* fcsum = (float*)(ws + 134481920);                       // 1048576
  float* sexp = (float*)(ws + 135530496);                        // 2097152 (2 partials)
  float* loss = (float*)(ws + 137627648);                        // 262144
  float* part = (float*)(ws + 137889792);                        // 8388608
  const size_t WS_NEED_PART = 137889792UL + 8388608UL;           // 146278400
  float* out = (float*)d_out;

  hipMemsetAsync(cnt, 0, GN * NSLOT * sizeof(int), stream);
  k_norm<<<NTOKENS / 4, 256, 0, stream>>>(ft, ftb);
  k_norm<<<NTOKENS / 4, 256, 0, stream>>>(fc, fcb);
  k_grp<<<NTOKENS / 256, 256, 0, stream>>>(masks, grp, cnt);
  if (ws_size >= WS_NEED_PART) {
    k_fcsum_part<<<GN * NCH, 256, 0, stream>>>(fcb, grp, part);
    k_fcsum_red<<<GN * NSLOT * CD / 256, 256, 0, stream>>>(part, fcsum);
  } else {
    k_fcsum<<<GN * 2, 256, 0, stream>>>(fcb, grp, fcsum);
  }
  k_pair<<<GN * (MT / BM) * 2, 256, 0, stream>>>(ftb, fcb, sexp);
  k_loss<<<1024, 256, 0, stream>>>(ftb, fcb, fcsum, grp, cnt, sexp, loss);
  k_reduce<<<1, 256, 0, stream>>>(loss, out);
}

// Round 4
// 414.624 us; speedup vs baseline: 2.6431x; 1.1924x over previous
//
#include <hip/hip_runtime.h>

#define GN 32
#define MT 2048
#define CD 512
#define NSLOT 16
#define NTOKENS 65536
#define SCALE -1.4285714285714286f

typedef short s16x8 __attribute__((ext_vector_type(8)));
typedef float f32x4 __attribute__((ext_vector_type(4)));

__device__ __forceinline__ float bf2f(unsigned short u) {
  return __uint_as_float(((unsigned)u) << 16);
}
__device__ __forceinline__ unsigned short f2bf(float f) {
  unsigned u = __float_as_uint(f);
  unsigned r = (u + 0x7fffu + ((u >> 16) & 1u)) >> 16;
  return (unsigned short)r;
}

typedef __attribute__((address_space(3))) unsigned lds_u32_t;
typedef __attribute__((address_space(1))) const unsigned glb_u32_t;

__device__ __forceinline__ void gload16(const unsigned short* g, unsigned short* l) {
  __builtin_amdgcn_global_load_lds((glb_u32_t*)g, (lds_u32_t*)l, 16, 0, 0);
}

// K1: L2-normalize rows of [NTOKENS, 512] fp32 -> bf16. One wave per row.
__global__ __launch_bounds__(256) void k_norm(const float* __restrict__ in,
                                              unsigned short* __restrict__ out) {
  int wid = threadIdx.x >> 6, lane = threadIdx.x & 63;
  long row = (long)blockIdx.x * 4 + wid;
  const float4* src = reinterpret_cast<const float4*>(in + row * CD);
  float4 v0 = src[lane];
  float4 v1 = src[64 + lane];
  float ss = v0.x * v0.x + v0.y * v0.y + v0.z * v0.z + v0.w * v0.w +
             v1.x * v1.x + v1.y * v1.y + v1.z * v1.z + v1.w * v1.w;
#pragma unroll
  for (int off = 32; off; off >>= 1) ss += __shfl_xor(ss, off);
  float rn = 1.0f / fmaxf(sqrtf(ss), 1e-12f);
  ushort4 o0, o1;
  o0.x = f2bf(v0.x * rn); o0.y = f2bf(v0.y * rn);
  o0.z = f2bf(v0.z * rn); o0.w = f2bf(v0.w * rn);
  o1.x = f2bf(v1.x * rn); o1.y = f2bf(v1.y * rn);
  o1.z = f2bf(v1.z * rn); o1.w = f2bf(v1.w * rn);
  ushort4* dst = reinterpret_cast<ushort4*>(out + row * CD);
  dst[lane] = o0;
  dst[64 + lane] = o1;
}

// K2: argmax over slot dim + per-(group,slot) histogram
__global__ __launch_bounds__(256) void k_grp(const float* __restrict__ masks,
                                             int* __restrict__ grp, int* __restrict__ cnt) {
  int t = blockIdx.x * 256 + threadIdx.x;  // t < 65536
  int bt = t >> 10, n = t & 1023;
  const float* p = masks + (size_t)bt * NSLOT * 1024 + n;
  float bv = p[0];
  int bs = 0;
#pragma unroll
  for (int s = 1; s < NSLOT; ++s) {
    float v = p[(size_t)s * 1024];
    if (v > bv) { bv = v; bs = s; }
  }
  grp[t] = bs;
  atomicAdd(&cnt[(t >> 11) * NSLOT + bs], 1);
}

// K3a: partial fcsum over row-chunks. block = (g, chunk of 256 rows); thread owns cols {2t, 2t+1}
#define FCH 256
#define NCH (MT / FCH)  // 8
__global__ __launch_bounds__(256) void k_fcsum_part(const unsigned short* __restrict__ fcb,
                                                    const int* __restrict__ grp,
                                                    float* __restrict__ part) {
  __shared__ int gsh[FCH];
  int g = blockIdx.x >> 3;
  int ch = blockIdx.x & 7;
  int t = threadIdx.x;
  gsh[t] = grp[g * MT + ch * FCH + t];
  __syncthreads();
  float ax[NSLOT], ay[NSLOT];
#pragma unroll
  for (int s = 0; s < NSLOT; ++s) { ax[s] = 0.f; ay[s] = 0.f; }
  const unsigned short* base = fcb + ((size_t)g * MT + ch * FCH) * CD + 2 * t;
  for (int n = 0; n < FCH; ++n) {
    unsigned u = *(const unsigned*)(base + (size_t)n * CD);
    float v0 = bf2f((unsigned short)(u & 0xffff));
    float v1 = bf2f((unsigned short)(u >> 16));
    int gs = gsh[n];
#pragma unroll
    for (int s = 0; s < NSLOT; ++s) {
      bool m = (gs == s);
      ax[s] += m ? v0 : 0.f;
      ay[s] += m ? v1 : 0.f;
    }
  }
  float* dst = part + ((size_t)(g * NCH + ch) * NSLOT) * CD + 2 * t;
#pragma unroll
  for (int s = 0; s < NSLOT; ++s) {
    dst[(size_t)s * CD] = ax[s];
    dst[(size_t)s * CD + 1] = ay[s];
  }
}

// K3b: reduce partials over the chunks
__global__ __launch_bounds__(256) void k_fcsum_red(const float* __restrict__ part,
                                                   float* __restrict__ fcsum) {
  int idx = blockIdx.x * 256 + threadIdx.x;  // < GN*NSLOT*CD = 262144
  int g = idx >> 13;
  int sc = idx & 8191;
  float s = 0.f;
#pragma unroll
  for (int ch = 0; ch < NCH; ++ch)
    s += part[((size_t)(g * NCH + ch) * NSLOT) * CD + sc];
  fcsum[idx] = s;
}

// K3 fallback (slow, no extra ws)
__global__ __launch_bounds__(256) void k_fcsum(const unsigned short* __restrict__ fcb,
                                               const int* __restrict__ grp,
                                               float* __restrict__ fcsum) {
  __shared__ int gsh[MT];
  int g = blockIdx.x >> 1;
  int c = (blockIdx.x & 1) * 256 + threadIdx.x;
  for (int i = threadIdx.x; i < MT; i += 256) gsh[i] = grp[g * MT + i];
  __syncthreads();
  float acc[NSLOT];
#pragma unroll
  for (int s = 0; s < NSLOT; ++s) acc[s] = 0.f;
  const unsigned short* base = fcb + (size_t)g * MT * CD + c;
  for (int n = 0; n < MT; ++n) {
    float v = bf2f(base[(size_t)n * CD]);
    int gs = gsh[n];
#pragma unroll
    for (int s = 0; s < NSLOT; ++s) acc[s] += (gs == s) ? v : 0.f;
  }
#pragma unroll
  for (int s = 0; s < NSLOT; ++s) fcsum[((size_t)g * NSLOT + s) * CD + c] = acc[s];
}

// K4: 256x256-tile pair kernel, 8 waves, depth-1 issue-early double buffer.
// Block = (g, row-tile of 256). Loops all 2048 cols in 8 col-tiles, K inner (8 BK-steps).
// Per tile: STAGE(next tile -> other buffer) first, then ds_read+MFMA from current,
// exp-epilogue every 8th tile, single __syncthreads (vmcnt drain) per tile.
#define BM 256
#define BN 256
#define BK 64
#define NTILE ((MT / BN) * (CD / BK))  // 64

__global__ __launch_bounds__(512, 2) void k_pair(const unsigned short* __restrict__ ftb,
                                                 const unsigned short* __restrict__ fcb,
                                                 float* __restrict__ sexp_out) {
  extern __shared__ unsigned short smem[];  // [A0 32K][A1 32K][B0 32K][B1 32K] bytes

  // XCD-grouped mapping: the 8 row-tile blocks of group g land on XCD g&7
  const int b = blockIdx.x;
  const int xcd = b & 7;
  const int slot = b >> 3;              // 0..31
  const int g = (slot >> 3) * 8 + xcd;  // 4 groups per XCD
  const int rt = slot & 7;
  const int r0 = rt * BM;

  const int tid = threadIdx.x;
  const int lane = tid & 63;
  const int wid = tid >> 6;      // 0..7
  const int wr = wid >> 2;       // 0..1  (M half)
  const int wc = wid & 3;        // 0..3  (N quarter)
  const int frow = lane & 15;
  const int ch = lane >> 4;      // 0..3
  const int f7 = frow & 7;

  const unsigned short* Abase = ftb + (size_t)g * MT * CD;
  const unsigned short* Bbase = fcb + (size_t)g * MT * CD;

  // staging per-lane source offset within a (rowblock, kk): row=lane>>3, chunk pre-swizzled
  const int lrow = lane >> 3;                       // 0..7
  const int koff = ((lane & 7) ^ lrow) << 3;        // element offset

  // frag-read swizzled byte addrs within a tile buffer
  const int aA0 = (wr * 128 + frow) * 128 + ((ch ^ f7) << 4);
  const int aA1 = (wr * 128 + frow) * 128 + (((4 | ch) ^ f7) << 4);
  const int aB0 = (wc * 64 + frow) * 128 + ((ch ^ f7) << 4);
  const int aB1 = (wc * 64 + frow) * 128 + (((4 | ch) ^ f7) << 4);
  const char* cS = (const char*)smem;

  f32x4 acc[8][4];
#pragma unroll
  for (int m = 0; m < 8; ++m)
#pragma unroll
    for (int n = 0; n < 4; ++n) acc[m][n] = (f32x4){0.f, 0.f, 0.f, 0.f};
  float sexp_loc[8][4];
#pragma unroll
  for (int m = 0; m < 8; ++m)
#pragma unroll
    for (int r = 0; r < 4; ++r) sexp_loc[m][r] = 0.f;

  // prologue: stage tile 0 into buffer 0
  {
    const int kk = 0, n0 = 0;
#pragma unroll
    for (int h = 0; h < 2; ++h)
#pragma unroll
      for (int i = 0; i < 2; ++i) {
        const int rb = h * 128 + wid * 16 + i * 8;
        gload16(Abase + (size_t)(r0 + rb + lrow) * CD + kk + koff, &smem[(size_t)rb * BK]);
        gload16(Bbase + (size_t)(n0 + rb + lrow) * CD + kk + koff,
                &smem[32768 + (size_t)rb * BK]);
      }
  }
  __syncthreads();

  int pb = 0;
  for (int t = 0; t < NTILE; ++t) {
    // issue next tile's stages into the other buffer (issue-early; latency hides under MFMA)
    if (t + 1 < NTILE) {
      const int t1 = t + 1;
      const int kk = (t1 & 7) * BK;
      const int n0 = (t1 >> 3) * BN;
      unsigned short* dA = &smem[(size_t)(pb ^ 1) * 16384];          // elems: 32KB/2
      unsigned short* dB = &smem[32768 + (size_t)(pb ^ 1) * 16384];  // elems
#pragma unroll
      for (int h = 0; h < 2; ++h)
#pragma unroll
        for (int i = 0; i < 2; ++i) {
          const int rb = h * 128 + wid * 16 + i * 8;
          gload16(Abase + (size_t)(r0 + rb + lrow) * CD + kk + koff, dA + (size_t)rb * BK);
          gload16(Bbase + (size_t)(n0 + rb + lrow) * CD + kk + koff, dB + (size_t)rb * BK);
        }
    }

    // compute current tile from buf[pb]
    const char* cA = cS + (size_t)pb * 32768;
    const char* cB = cS + 65536 + (size_t)pb * 32768;
    __builtin_amdgcn_s_setprio(1);
#pragma unroll
    for (int ks = 0; ks < 2; ++ks) {
      s16x8 af[8], bfv[4];
      const int aA = ks ? aA1 : aA0;
      const int aB = ks ? aB1 : aB0;
#pragma unroll
      for (int n = 0; n < 4; ++n) bfv[n] = *(const s16x8*)(cB + aB + n * 2048);
#pragma unroll
      for (int m = 0; m < 8; ++m) af[m] = *(const s16x8*)(cA + aA + m * 2048);
#pragma unroll
      for (int m = 0; m < 8; ++m)
#pragma unroll
        for (int n = 0; n < 4; ++n)
          acc[m][n] = __builtin_amdgcn_mfma_f32_16x16x32_bf16(af[m], bfv[n], acc[m][n], 0, 0, 0);
    }
    __builtin_amdgcn_s_setprio(0);

    // every 8th tile: col-tile done -> exp-accumulate (VALU work fills the drain window)
    if ((t & 7) == 7) {
#pragma unroll
      for (int m = 0; m < 8; ++m)
#pragma unroll
        for (int r = 0; r < 4; ++r) {
          float e = 0.f;
#pragma unroll
          for (int n = 0; n < 4; ++n) e += __expf(acc[m][n][r] * 10.0f);
          sexp_loc[m][r] += e;
        }
#pragma unroll
      for (int m = 0; m < 8; ++m)
#pragma unroll
        for (int n = 0; n < 4; ++n) acc[m][n] = (f32x4){0.f, 0.f, 0.f, 0.f};
    }

    __syncthreads();  // drains my gloads (vmcnt 0) + all waves done reading buf[pb]
    pb ^= 1;
  }

  // reduce sexp over the 16 column-lanes of each frag
#pragma unroll
  for (int m = 0; m < 8; ++m)
#pragma unroll
    for (int r = 0; r < 4; ++r) {
      float v = sexp_loc[m][r];
      v += __shfl_xor(v, 1);
      v += __shfl_xor(v, 2);
      v += __shfl_xor(v, 4);
      v += __shfl_xor(v, 8);
      sexp_loc[m][r] = v;
    }
  // cross-wave reduce over the 4 wc-waves via LDS scratch (reuse buffer A0 region)
  float* scr = (float*)smem;  // [8 waves][128 rows]
  if (frow == 0) {
#pragma unroll
    for (int m = 0; m < 8; ++m)
#pragma unroll
      for (int r = 0; r < 4; ++r) scr[wid * 128 + m * 16 + ch * 4 + r] = sexp_loc[m][r];
  }
  __syncthreads();
  if (tid < 256) {
    int wrr = tid >> 7, rl = tid & 127;
    float s = scr[(wrr * 4 + 0) * 128 + rl] + scr[(wrr * 4 + 1) * 128 + rl] +
              scr[(wrr * 4 + 2) * 128 + rl] + scr[(wrr * 4 + 3) * 128 + rl];
    sexp_out[(size_t)g * MT + r0 + tid] = s;
  }
}

// K5: per-token loss using diag dot, slot-sum dot, lse, counts
__global__ __launch_bounds__(256) void k_loss(const unsigned short* __restrict__ ftb,
                                              const unsigned short* __restrict__ fcb,
                                              const float* __restrict__ fcsum,
                                              const int* __restrict__ grp,
                                              const int* __restrict__ cnt,
                                              const float* __restrict__ sexp,
                                              float* __restrict__ loss) {
  int wid = threadIdx.x >> 6, lane = threadIdx.x & 63;
  for (int t = blockIdx.x * 4 + wid; t < NTOKENS; t += 4096) {
    int g = t >> 11;
    const unsigned short* fr = ftb + (size_t)t * CD;
    const unsigned short* cr = fcb + (size_t)t * CD;
    int gs = grp[t];
    const float* sr = fcsum + ((size_t)g * NSLOT + gs) * CD;
    float d1 = 0.f, d2 = 0.f;
#pragma unroll
    for (int j = 0; j < 8; ++j) {
      int c = lane + j * 64;
      float fv = bf2f(fr[c]);
      d1 += fv * bf2f(cr[c]);
      d2 += fv * sr[c];
    }
#pragma unroll
    for (int off = 32; off; off >>= 1) {
      d1 += __shfl_xor(d1, off);
      d2 += __shfl_xor(d2, off);
    }
    if (lane == 0) {
      float lse = __logf(sexp[t]);
      float cm = (float)cnt[g * NSLOT + gs];
      float semi = SCALE * (d2 * 10.0f / cm - lse);
      float pos = SCALE * (d1 * 10.0f - lse);
      loss[t] = 0.5f * (semi + pos);
    }
  }
}

// K6: final mean
__global__ __launch_bounds__(256) void k_reduce(const float* __restrict__ loss,
                                                float* __restrict__ out) {
  __shared__ float sh[4];
  float s = 0.f;
  for (int i = threadIdx.x; i < NTOKENS; i += 256) s += loss[i];
#pragma unroll
  for (int off = 32; off; off >>= 1) s += __shfl_xor(s, off);
  if ((threadIdx.x & 63) == 0) sh[threadIdx.x >> 6] = s;
  __syncthreads();
  if (threadIdx.x == 0) out[0] = (sh[0] + sh[1] + sh[2] + sh[3]) * (1.0f / NTOKENS);
}

extern "C" void kernel_launch(void* const* d_in, const int* in_sizes, int n_in,
                              void* d_out, int out_size, void* d_ws, size_t ws_size,
                              hipStream_t stream) {
  const float* ft = (const float*)d_in[0];
  const float* fc = (const float*)d_in[1];
  const float* masks = (const float*)d_in[2];
  char* ws = (char*)d_ws;

  // workspace layout (bytes)
  unsigned short* ftb = (unsigned short*)(ws);                   // 67108864
  unsigned short* fcb = (unsigned short*)(ws + 67108864);        // 67108864
  int* grp = (int*)(ws + 134217728);                             // 262144
  int* cnt = (int*)(ws + 134479872);                             // 2048
  float* fcsum = (float*)(ws + 134481920);                       // 1048576
  float* sexp = (float*)(ws + 135530496);                        // 262144
  float* loss = (float*)(ws + 137627648);                        // 262144
  float* part = (float*)(ws + 137889792);                        // 8388608
  const size_t WS_NEED_PART = 137889792UL + 8388608UL;           // 146278400
  float* out = (float*)d_out;

  static int lds_attr_set = 0;
  if (!lds_attr_set) {
    hipFuncSetAttribute((const void*)k_pair, hipFuncAttributeMaxDynamicSharedMemorySize,
                        131072);
    lds_attr_set = 1;
  }

  hipMemsetAsync(cnt, 0, GN * NSLOT * sizeof(int), stream);
  k_norm<<<NTOKENS / 4, 256, 0, stream>>>(ft, ftb);
  k_norm<<<NTOKENS / 4, 256, 0, stream>>>(fc, fcb);
  k_grp<<<NTOKENS / 256, 256, 0, stream>>>(masks, grp, cnt);
  if (ws_size >= WS_NEED_PART) {
    k_fcsum_part<<<GN * NCH, 256, 0, stream>>>(fcb, grp, part);
    k_fcsum_red<<<GN * NSLOT * CD / 256, 256, 0, stream>>>(part, fcsum);
  } else {
    k_fcsum<<<GN * 2, 256, 0, stream>>>(fcb, grp, fcsum);
  }
  k_pair<<<GN * (MT / BM), 512, 131072, stream>>>(ftb, fcb, sexp);
  k_loss<<<1024, 256, 0, stream>>>(ftb, fcb, fcsum, grp, cnt, sexp, loss);
  k_reduce<<<1, 256, 0, stream>>>(loss, out);
}